// Round 1
// baseline (8612.896 us; speedup 1.0000x reference)
//
#include <hip/hip_runtime.h>

#define T_STEPS 256
#define NBATCH  256
#define HID     1024
#define KTOT    2048

typedef short bf16x8 __attribute__((ext_vector_type(8)));
typedef float f32x4  __attribute__((ext_vector_type(4)));

__device__ inline short cvt_bf16(float f) {
  unsigned u = __builtin_bit_cast(unsigned, f);
  u += 0x7fffu + ((u >> 16) & 1u);   // round-to-nearest-even
  return (short)(u >> 16);
}

__device__ inline float fast_sigmoid(float x) {
  return __builtin_amdgcn_rcpf(1.0f + __builtin_amdgcn_exp2f(-1.44269504f * x));
}
__device__ inline float fast_tanh(float x) {
  return 2.0f * __builtin_amdgcn_rcpf(1.0f + __builtin_amdgcn_exp2f(-2.88539008f * x)) - 1.0f;
}

// ---------------------------------------------------------------------------
// Tiled layouts (MFMA-fragment contiguous):
//   Wbig: [ug 64][k32 64][ui 4][lane 64][8]  (lane = kq*16 + n_row, elems j=k&7)
//   x:    [mtile 16][k32 64][lane 64][8]     (lane = kq*16 + m_row)
// One wave-load of 16B/lane reads exactly one contiguous 1KB subtile.
// Logical row permutation unchanged: u' = ug*64 + g*16 + uu.
// ---------------------------------------------------------------------------

// ---- K1: Whh -> Wbig right half (tiled); Wfc cast; x0 build ---------------
__global__ void cast_kernel(const float* __restrict__ Whh,
                            const float* __restrict__ Wfc,
                            const float* __restrict__ cvec,
                            short* __restrict__ Wbig,
                            short* __restrict__ Wfcb,
                            short* __restrict__ x0) {
  long i = (long)blockIdx.x * blockDim.x + threadIdx.x;   // float4 quad index
  const long nWhh = 4096L * 1024 / 4;   // 1048576
  const long nWfc = 1024L * 1024 / 4;   // 262144
  const long nX0  = 256L * KTOT / 4;    // 131072
  if (i < nWhh) {
    int in_row = (int)(i >> 8);
    int c4 = ((int)i & 255) * 4;
    int g = in_row >> 10, rem = in_row & 1023, ug = rem >> 4, uu = rem & 15;
    int k = 1024 + c4;                  // right half of K
    int k32 = k >> 5, kq = (k >> 3) & 3, j = k & 7;
    float4 v = *(const float4*)(Whh + (long)in_row * 1024 + c4);
    short4 o;
    o.x = cvt_bf16(v.x); o.y = cvt_bf16(v.y); o.z = cvt_bf16(v.z); o.w = cvt_bf16(v.w);
    long dst = ((((long)(ug * 64 + k32) * 4 + g) * 64) + kq * 16 + uu) * 8 + j;
    *(short4*)(Wbig + dst) = o;
  } else if (i < nWhh + nWfc) {
    long q = i - nWhh;
    float4 v = ((const float4*)Wfc)[q];
    short4 o;
    o.x = cvt_bf16(v.x); o.y = cvt_bf16(v.y); o.z = cvt_bf16(v.z); o.w = cvt_bf16(v.w);
    *(short4*)(Wfcb + q * 4) = o;
  } else if (i < nWhh + nWfc + nX0) {
    long q = i - nWhh - nWfc;
    int m = (int)(q >> 9);              // 512 quads per 2048-col row
    int c4 = ((int)q & 511) * 4;
    short4 o;
    if (c4 < 1024) {                    // c-part is zero at t=0 (i0 = 0 fold)
      o.x = o.y = o.z = o.w = 0;
    } else {
      float4 v = *(const float4*)(cvec + (long)m * 1024 + (c4 - 1024));
      o.x = cvt_bf16(v.x); o.y = cvt_bf16(v.y); o.z = cvt_bf16(v.z); o.w = cvt_bf16(v.w);
    }
    int k32 = c4 >> 5, kq = (c4 >> 3) & 3, j = c4 & 7;
    int mtile = m >> 4, mrow = m & 15;
    long dst = (((long)mtile * 64 + k32) * 64 + kq * 16 + mrow) * 8 + j;
    *(short4*)(x0 + dst) = o;
  }
}

// ---- K2: b0 = b_ih+b_hh ; bc = b0 + W_ih @ b_fc  (permuted to u') ---------
__global__ void bias_kernel(const float* __restrict__ W_ih,
                            const float* __restrict__ b_ih,
                            const float* __restrict__ b_hh,
                            const float* __restrict__ b_fc,
                            float* __restrict__ b0r, float* __restrict__ bcr) {
  int w = threadIdx.x >> 6, l = threadIdx.x & 63;
  int n = blockIdx.x * 4 + w;          // 4096 rows, 4 waves/block
  const float* row = W_ih + (long)n * HID;
  float s = 0.f;
  for (int i = l; i < HID; i += 64) s += row[i] * b_fc[i];
  #pragma unroll
  for (int off = 32; off; off >>= 1) s += __shfl_xor(s, off, 64);
  if (l == 0) {
    int g = n >> 10, uidx = n & 1023, ug = uidx >> 4, uu = uidx & 15;
    int up = ug * 64 + g * 16 + uu;
    float base = b_ih[n] + b_hh[n];
    b0r[up] = base;
    bcr[up] = base + s;
  }
}

// ---- K3: Wc = W_ih @ W_fc -> Wbig left half (tiled, bf16) -----------------
__global__ void wc_kernel(const float* __restrict__ W_ih,
                          const float* __restrict__ W_fc,
                          short* __restrict__ Wbig) {
  int w = threadIdx.x >> 6, l = threadIdx.x & 63;
  int tile = blockIdx.x * 4 + w;       // 16384 tiles: 256 n-tiles x 64 k-tiles
  int nt = tile >> 6, kt = tile & 63;
  int lr = l & 15, lq = l >> 4;
  f32x4 acc = {0.f, 0.f, 0.f, 0.f};
  const float* arow = W_ih + (long)(nt * 16 + lr) * HID + lq * 8;
  const float* bcol = W_fc + (long)(lq * 8) * HID + kt * 16 + lr;
  for (int jc = 0; jc < HID; jc += 32) {
    float4 a0 = *(const float4*)(arow + jc);
    float4 a1 = *(const float4*)(arow + jc + 4);
    bf16x8 a;
    a[0]=cvt_bf16(a0.x); a[1]=cvt_bf16(a0.y); a[2]=cvt_bf16(a0.z); a[3]=cvt_bf16(a0.w);
    a[4]=cvt_bf16(a1.x); a[5]=cvt_bf16(a1.y); a[6]=cvt_bf16(a1.z); a[7]=cvt_bf16(a1.w);
    bf16x8 b;
    #pragma unroll
    for (int jj = 0; jj < 8; ++jj) b[jj] = cvt_bf16(bcol[(long)(jc + jj) * HID]);
    acc = __builtin_amdgcn_mfma_f32_16x16x32_bf16(a, b, acc, 0, 0, 0);
  }
  int k = kt * 16 + lr;                // col in [0,1024) -> left half of K
  int g = nt >> 6, ug = nt & 63;
  int k32 = k >> 5, kq = (k >> 3) & 3, j = k & 7;
  #pragma unroll
  for (int r = 0; r < 4; ++r) {
    long dst = ((((long)(ug * 64 + k32) * 4 + g) * 64) + kq * 16 + (lq * 4 + r)) * 8 + j;
    Wbig[dst] = cvt_bf16(acc[r]);
  }
}

// ---- per-step: [64m x 64 gate-cols] per block, split-K over 8 waves -------
// 512 threads = 8 waves = 2 waves/SIMD (latency hiding). All loads are
// contiguous 16B/lane from the tiled layouts. Two-phase LDS split-K
// reduction keeps LDS at 64 KB.
__global__ __launch_bounds__(512, 2)
void step_kernel(int t,
                 const short* __restrict__ x,      // tiled [16][64][64][8] bf16
                 const short* __restrict__ Wbig,   // tiled [64][64][4][64][8] bf16
                 const float* __restrict__ bias,   // [4096] permuted
                 const float* __restrict__ cprev,  // fp32, row-stride cprev_rs
                 long cprev_rs,
                 float* __restrict__ hst, float* __restrict__ cst,
                 short* __restrict__ xnext) {
  int tid = threadIdx.x;
  int w = tid >> 6, l = tid & 63, lr = l & 15, lq = l >> 4;
  int b = blockIdx.x;
  int ug = (b & 7) * 8 + ((b >> 3) & 7);   // XCD-contiguous weight stripes
  int mg = b >> 6;

  // epilogue operands hoisted above the K-loop (latency hidden under MFMAs)
  int unit = ug * 16 + lr;
  float c_old[4], bi = 0.f, bff = 0.f, bg = 0.f, bo = 0.f;
  if (w < 4) {
    bi  = bias[ug * 64 +  0 + lr];
    bff = bias[ug * 64 + 16 + lr];
    bg  = bias[ug * 64 + 32 + lr];
    bo  = bias[ug * 64 + 48 + lr];
    #pragma unroll
    for (int r = 0; r < 4; ++r) {
      int m = mg * 64 + w * 16 + lq * 4 + r;
      c_old[r] = cprev[(long)m * cprev_rs + unit];
    }
  }

  // wave w owns K slice [w*256, w*256+256) -> k32 = w*8 + it, it in [0,8)
  const short* ab = x    + ((long)(mg * 4) * 64 + w * 8) * 512 + l * 8;
  const short* bb = Wbig + ((long)(ug * 64 + w * 8) * 4) * 512 + l * 8;

  f32x4 acc[4][4] = {};
  bf16x8 af[2][4], bfr[2][4];
  #pragma unroll
  for (int i = 0; i < 4; ++i) {
    af[0][i]  = *(const bf16x8*)(ab + (long)i * 32768);
    bfr[0][i] = *(const bf16x8*)(bb + (long)i * 512);
  }
  #pragma unroll
  for (int it = 0; it < 8; ++it) {
    const int cur = it & 1, nxt = cur ^ 1;
    if (it < 7) {
      #pragma unroll
      for (int i = 0; i < 4; ++i) {
        af[nxt][i]  = *(const bf16x8*)(ab + (long)(it + 1) * 512 + (long)i * 32768);
        bfr[nxt][i] = *(const bf16x8*)(bb + (long)(it + 1) * 2048 + (long)i * 512);
      }
    }
    #pragma unroll
    for (int mi = 0; mi < 4; ++mi)
      #pragma unroll
      for (int ui = 0; ui < 4; ++ui)
        acc[mi][ui] = __builtin_amdgcn_mfma_f32_16x16x32_bf16(af[cur][mi], bfr[cur][ui], acc[mi][ui], 0, 0, 0);
  }

  // two-phase split-K reduction (64 KB LDS)
  __shared__ f32x4 lds4[4 * 4 * 4 * 64];
  if (w >= 4) {
    #pragma unroll
    for (int mi = 0; mi < 4; ++mi)
      #pragma unroll
      for (int ui = 0; ui < 4; ++ui)
        lds4[(((w - 4) * 4 + mi) * 4 + ui) * 64 + l] = acc[mi][ui];
  }
  __syncthreads();
  if (w < 4) {
    #pragma unroll
    for (int mi = 0; mi < 4; ++mi)
      #pragma unroll
      for (int ui = 0; ui < 4; ++ui) {
        acc[mi][ui] += lds4[((w * 4 + mi) * 4 + ui) * 64 + l];
        if (mi != w)
          lds4[((w * 4 + mi) * 4 + ui) * 64 + l] = acc[mi][ui];
      }
  }
  __syncthreads();
  if (w < 4) {
    f32x4 red[4];
    #pragma unroll
    for (int ui = 0; ui < 4; ++ui) {
      red[ui] = acc[w][ui];
      #pragma unroll
      for (int wv = 0; wv < 4; ++wv)
        if (wv != w) red[ui] += lds4[((wv * 4 + w) * 4 + ui) * 64 + l];
    }

    // fused LSTM cell: gate quadruple is in-lane across ui
    int mtile = mg * 4 + w;
    int k32c = ug >> 1;
    int kqc = (ug & 1) * 2 + (lr >> 3);
    int jc = lr & 7;
    long xbase = ((((long)mtile * 64 + k32c) * 64) + kqc * 16) * 8 + jc;
    #pragma unroll
    for (int r = 0; r < 4; ++r) {
      int m = mg * 64 + w * 16 + lq * 4 + r;
      float ig = fast_sigmoid(red[0][r] + bi);
      float fg = fast_sigmoid(red[1][r] + bff);
      float gg = fast_tanh(red[2][r] + bg);
      float og = fast_sigmoid(red[3][r] + bo);
      float cn = fg * c_old[r] + ig * gg;
      float hn = og * fast_tanh(cn);
      long o = ((long)m * T_STEPS + t) * HID + unit;
      __builtin_nontemporal_store(hn, &hst[o]);   // keep L2 for weights
      __builtin_nontemporal_store(cn, &cst[o]);
      int mrow = lq * 4 + r;
      xnext[xbase + (long)mrow * 8]         = cvt_bf16(cn);  // c-half (k32c)
      xnext[xbase + (long)mrow * 8 + 16384] = cvt_bf16(hn);  // h-half (+32 k32)
    }
  }
}

// ---- K4: outputs = c_states @ W_fc.T + b_fc  (A read fp32 from cst) -------
__global__ void fc_kernel(const float* __restrict__ A,      // [65536,1024] rows = b*256+t
                          const short* __restrict__ Bw,     // W_fc bf16 [1024,1024]
                          const float* __restrict__ b_fc,
                          float* __restrict__ out) {
  int w = threadIdx.x >> 6, l = threadIdx.x & 63;
  int wave = blockIdx.x * 4 + w;       // 16384 waves: 1024 m-tiles x 16 u-tiles
  int ut = wave & 15, mt = wave >> 4;
  int lr = l & 15, lq = l >> 4;
  f32x4 acc[4][4] = {};
  const float* arow[4]; const short* brow[4];
  #pragma unroll
  for (int i = 0; i < 4; ++i) {
    arow[i] = A  + (long)(mt * 64 + i * 16 + lr) * HID + lq * 8;
    brow[i] = Bw + (long)(ut * 64 + i * 16 + lr) * HID + lq * 8;
  }
  for (int kc = 0; kc < HID; kc += 32) {
    bf16x8 a[4], b[4];
    #pragma unroll
    for (int i = 0; i < 4; ++i) {
      float4 v0 = *(const float4*)(arow[i] + kc);
      float4 v1 = *(const float4*)(arow[i] + kc + 4);
      bf16x8 r;
      r[0]=cvt_bf16(v0.x); r[1]=cvt_bf16(v0.y); r[2]=cvt_bf16(v0.z); r[3]=cvt_bf16(v0.w);
      r[4]=cvt_bf16(v1.x); r[5]=cvt_bf16(v1.y); r[6]=cvt_bf16(v1.z); r[7]=cvt_bf16(v1.w);
      a[i] = r;
      b[i] = *(const bf16x8*)(brow[i] + kc);
    }
    #pragma unroll
    for (int mi = 0; mi < 4; ++mi)
      #pragma unroll
      for (int ui = 0; ui < 4; ++ui)
        acc[mi][ui] = __builtin_amdgcn_mfma_f32_16x16x32_bf16(a[mi], b[ui], acc[mi][ui], 0, 0, 0);
  }
  int u0 = ut * 64;
  #pragma unroll
  for (int ui = 0; ui < 4; ++ui) {
    float bf = b_fc[u0 + ui * 16 + lr];
    #pragma unroll
    for (int mi = 0; mi < 4; ++mi)
      #pragma unroll
      for (int r = 0; r < 4; ++r) {
        long mo = (long)mt * 64 + mi * 16 + lq * 4 + r;
        __builtin_nontemporal_store(acc[mi][ui][r] + bf,
                                    &out[mo * HID + u0 + ui * 16 + lr]);
      }
  }
}

// ---------------------------------------------------------------------------
extern "C" void kernel_launch(void* const* d_in, const int* in_sizes, int n_in,
                              void* d_out, int out_size, void* d_ws, size_t ws_size,
                              hipStream_t stream) {
  const float* cvec = (const float*)d_in[0];
  const float* W_ih = (const float*)d_in[1];
  const float* W_hh = (const float*)d_in[2];
  const float* b_ih = (const float*)d_in[3];
  const float* b_hh = (const float*)d_in[4];
  const float* W_fc = (const float*)d_in[5];
  const float* b_fc = (const float*)d_in[6];
  float* out = (float*)d_out;
  float* hst = out;
  float* cst = out + (long)NBATCH * T_STEPS * HID;
  float* ost = out + 2L * NBATCH * T_STEPS * HID;

  char* base = (char*)d_ws;
  size_t off = 0;
  auto carve = [&](size_t bytes) -> char* {
    char* r = base + off;
    off = (off + bytes + 255) & ~(size_t)255;
    return r;
  };
  short* Wbig = (short*)carve(4096L * KTOT * 2);      // 16 MB (tiled)
  short* Wfcb = (short*)carve(1024L * 1024 * 2);      // 2 MB
  float* b0r  = (float*)carve(4096 * 4);
  float* bcr  = (float*)carve(4096 * 4);
  short* xb[2];
  xb[0] = (short*)carve((long)NBATCH * KTOT * 2);     // 1 MB (tiled)
  xb[1] = (short*)carve((long)NBATCH * KTOT * 2);     // 1 MB (tiled)

  cast_kernel<<<5632, 256, 0, stream>>>(W_hh, W_fc, cvec, Wbig, Wfcb, xb[0]);
  bias_kernel<<<1024, 256, 0, stream>>>(W_ih, b_ih, b_hh, b_fc, b0r, bcr);
  wc_kernel<<<4096, 256, 0, stream>>>(W_ih, W_fc, Wbig);

  for (int t = 0; t < T_STEPS; ++t) {
    const float* cprev = (t == 0) ? cvec : (cst + (long)(t - 1) * HID);
    long cprev_rs = (t == 0) ? (long)HID : (long)T_STEPS * HID;
    const float* bias = (t == 0) ? b0r : bcr;
    step_kernel<<<256, 512, 0, stream>>>(t, xb[t & 1], Wbig, bias,
                                         cprev, cprev_rs, hst, cst,
                                         xb[(t + 1) & 1]);
  }
  fc_kernel<<<4096, 256, 0, stream>>>(cst, Wfcb, b_fc, ost);
}